// Round 7
// baseline (235.234 us; speedup 1.0000x reference)
//
#include <hip/hip_runtime.h>
#include <hip/hip_bf16.h>
#include <hip/hip_fp16.h>
#include <math.h>

#define B_ 8
#define N_ 2048
#define F_ 128

typedef __attribute__((ext_vector_type(8))) _Float16 half8;
typedef __attribute__((ext_vector_type(4))) float f32x4;

// async global->LDS, 16B per lane (global_load_lds_dwordx4)
__device__ __forceinline__ void gl2lds16(const void* g, void* l)
{
    __builtin_amdgcn_global_load_lds(
        (const __attribute__((address_space(1))) unsigned int*)g,
        (__attribute__((address_space(3))) unsigned int*)l, 16, 0, 0);
}

// ---------------------------------------------------------------------------
// Kernel 1: Wh = h @ W^T (fp32), fp16 B-frag swizzled out; exact fp32 sv/tv.
// WhH layout: element (b, j, o) at ((b*64 + j/32)*128 + o)*32 + ((j/8)%4)*8
// + (j%8)  -> each 32-j chunk is one contiguous 8 KB block.
// ---------------------------------------------------------------------------
__global__ __launch_bounds__(256) void k_gemm(
    const float* __restrict__ h, const float* __restrict__ W,
    const float* __restrict__ a,
    _Float16* __restrict__ WhH, float* __restrict__ sv, float* __restrict__ tv)
{
    __shared__ float h_s[64][129];
    __shared__ float Wt[128][68];
    __shared__ float wsm[128], wtm[128];
    __shared__ float sred[64][4], tred[64][4];

    const int t = threadIdx.x;
    const int rowblk = blockIdx.x >> 1;
    const int ohalf  = blockIdx.x & 1;
    const int r0 = rowblk * 64;

    {
        const int f = (t & 31) * 4;
        #pragma unroll
        for (int it = 0; it < 8; ++it) {
            const int r = (t >> 5) + it * 8;
            float4 v = *(const float4*)&h[(size_t)(r0 + r) * F_ + f];
            h_s[r][f] = v.x; h_s[r][f + 1] = v.y;
            h_s[r][f + 2] = v.z; h_s[r][f + 3] = v.w;
        }
    }
    {
        const int f = (t & 31) * 4;
        #pragma unroll
        for (int it = 0; it < 8; ++it) {
            const int o = (t >> 5) + it * 8;
            float4 v = *(const float4*)&W[(size_t)(ohalf * 64 + o) * F_ + f];
            Wt[f][o] = v.x; Wt[f + 1][o] = v.y;
            Wt[f + 2][o] = v.z; Wt[f + 3][o] = v.w;
        }
    }
    {
        const int f = t & 127;
        const int which = t >> 7;
        const float* av = a + which * 128;
        float acc = 0.f;
        for (int o = 0; o < 128; ++o)
            acc += W[(size_t)o * F_ + f] * av[o];
        if (which == 0) wsm[f] = acc; else wtm[f] = acc;
    }
    __syncthreads();

    const int o4 = t & 15;
    const int r4 = t >> 4;
    float acc[4][4];
    #pragma unroll
    for (int i = 0; i < 4; ++i)
        #pragma unroll
        for (int j = 0; j < 4; ++j) acc[i][j] = 0.f;

    #pragma unroll 4
    for (int k = 0; k < 128; ++k) {
        float4 w = *(const float4*)&Wt[k][o4 * 4];
        float h0 = h_s[r4 * 4 + 0][k];
        float h1 = h_s[r4 * 4 + 1][k];
        float h2 = h_s[r4 * 4 + 2][k];
        float h3 = h_s[r4 * 4 + 3][k];
        acc[0][0] += h0 * w.x; acc[0][1] += h0 * w.y; acc[0][2] += h0 * w.z; acc[0][3] += h0 * w.w;
        acc[1][0] += h1 * w.x; acc[1][1] += h1 * w.y; acc[1][2] += h1 * w.z; acc[1][3] += h1 * w.w;
        acc[2][0] += h2 * w.x; acc[2][1] += h2 * w.y; acc[2][2] += h2 * w.z; acc[2][3] += h2 * w.w;
        acc[3][0] += h3 * w.x; acc[3][1] += h3 * w.y; acc[3][2] += h3 * w.z; acc[3][3] += h3 * w.w;
    }

    {
        const int Rbase = r0 + r4 * 4;
        const int b    = Rbase >> 11;
        const int jj   = Rbase & 2047;
        const int jblk = jj >> 5;
        const int k8   = (jj >> 3) & 3;
        const int kk   = jj & 7;
        #pragma unroll
        for (int jo = 0; jo < 4; ++jo) {
            const int o = ohalf * 64 + o4 * 4 + jo;
            size_t off = ((size_t)(b * 64 + jblk) * 128 + o) * 32 + k8 * 8 + kk;
            union { _Float16 x[4]; uint2 u; } pk;
            pk.x[0] = (_Float16)acc[0][jo];
            pk.x[1] = (_Float16)acc[1][jo];
            pk.x[2] = (_Float16)acc[2][jo];
            pk.x[3] = (_Float16)acc[3][jo];
            *(uint2*)(WhH + off) = pk.u;
        }
    }

    {
        const int r = t & 63, part = t >> 6;
        float as_ = 0.f, at_ = 0.f;
        const int kb = part * 32;
        for (int k = kb; k < kb + 32; ++k) {
            float hv = h_s[r][k];
            as_ += hv * wsm[k];
            at_ += hv * wtm[k];
        }
        sred[r][part] = as_; tred[r][part] = at_;
    }
    __syncthreads();
    if (ohalf == 0 && t < 64) {
        sv[r0 + t] = sred[t][0] + sred[t][1] + sred[t][2] + sred[t][3];
        tv[r0 + t] = tred[t][0] + tred[t][1] + tred[t][2] + tred[t][3];
    }
}

// ---------------------------------------------------------------------------
// Kernel 2: flash-GAT, m97-style async-staged K-loop.
// 1024 blocks = 8 batch x 32 i-tiles(64 rows) x 4 j-slices(512 j); 4/CU.
// Per 32-j chunk, global_load_lds (async, 16B) stages BOTH the 8 KB WhH
// B-frag block and the 8 KB adj tile (XOR-swizzled slots: global side stays
// 128B-line coalesced, LDS reads land on distinct banks).  Double-buffered,
// ONE barrier per iteration; wave wv owns rows i0+wv*16 (one A-frag).
// Writes partial O (C-frag layout) + partial l per j-slice.
// ---------------------------------------------------------------------------
__global__ __launch_bounds__(256, 4) void k_attn(
    const _Float16* __restrict__ WhH, const float* __restrict__ sv,
    const float* __restrict__ tv, const int* __restrict__ adj,
    float* __restrict__ Po, float* __restrict__ Pl)
{
    __shared__ _Float16 whS[2][4096];    // 2 x 8 KB
    __shared__ int      adjS[2][2048];   // 2 x 8 KB
    __shared__ float    tS[512];
    __shared__ float    tmr[4];

    const int t   = threadIdx.x;
    const int b   = blockIdx.x & 7;      // XCD-swizzle heuristic
    const int rem = blockIdx.x >> 3;
    const int i0  = (rem & 31) * 64;
    const int jh  = rem >> 5;            // 0..3
    const int jbase = jh * 512;

    const float* tb = tv + ((size_t)b << 11);

    // per-batch tmax (full batch, L2-hot 8 KB)
    float tm = -INFINITY;
    #pragma unroll
    for (int k = 0; k < 8; ++k) tm = fmaxf(tm, tb[t + k * 256]);
    #pragma unroll
    for (int k = 32; k; k >>= 1) tm = fmaxf(tm, __shfl_xor(tm, k, 64));
    if ((t & 63) == 0) tmr[t >> 6] = tm;

    // stage t-slice (512 floats)
    tS[t]       = tb[jbase + t];
    tS[t + 256] = tb[jbase + t + 256];

    const int wv   = t >> 6;
    const int lane = t & 63;
    const int m_   = lane & 15;
    const int q_   = lane >> 4;

    const int   girow = (b << 11) + i0 + wv * 16 + m_;
    const float s_i   = sv[girow];

    const int*      adjb = adj + ((size_t)((b << 11) + i0) << 11) + jbase;
    const _Float16* whc  = WhH + (((size_t)b * 64 + jh * 16) << 12);

    // staging slots: thread t handles slots t and t+256 (512 x 16B per tile)
    const int s0 = t, s1 = t + 256;
    const int r0_ = s0 >> 3, g0 = (s0 & 7) ^ (r0_ & 7);
    const int r1_ = s1 >> 3, g1 = (s1 & 7) ^ (r1_ & 7);
    const int* a0p = adjb + (size_t)r0_ * N_ + g0 * 4;
    const int* a1p = adjb + (size_t)r1_ * N_ + g1 * 4;

    // ---- prologue: stage chunk 0 into buf 0 ----
    gl2lds16(whc + s0 * 8, &whS[0][s0 * 8]);
    gl2lds16(whc + s1 * 8, &whS[0][s1 * 8]);
    gl2lds16(a0p,          &adjS[0][s0 * 4]);
    gl2lds16(a1p,          &adjS[0][s1 * 4]);
    __syncthreads();     // drains staging + tS/tmr visible

    const float tmax = fmaxf(fmaxf(tmr[0], tmr[1]), fmaxf(tmr[2], tmr[3]));
    const float M_i  = fmaxf(s_i + tmax, 0.f);   // upper bound on leaky(s+t)

    // LDS read slots for this lane's adj (XOR-swizzled, ~2-way banks)
    const int r_  = wv * 16 + m_;
    const int sl0 = r_ * 8 + ((2 * q_)     ^ (r_ & 7));
    const int sl1 = r_ * 8 + ((2 * q_ + 1) ^ (r_ & 7));

    f32x4 acc[8];
    #pragma unroll
    for (int n = 0; n < 8; ++n) acc[n] = (f32x4){0.f, 0.f, 0.f, 0.f};
    float lsum = 0.f;

    for (int jj = 0; jj < 16; ++jj) {
        const int cur = jj & 1;
        const int nxt = (jj + 1) & 15;           // wrap re-stage: harmless

        // async stage of next chunk into the other buffer
        const _Float16* whn = whc + ((size_t)nxt << 12);
        const int joff = nxt * 32;
        gl2lds16(whn + s0 * 8,  &whS[cur ^ 1][s0 * 8]);
        gl2lds16(whn + s1 * 8,  &whS[cur ^ 1][s1 * 8]);
        gl2lds16(a0p + joff,    &adjS[cur ^ 1][s0 * 4]);
        gl2lds16(a1p + joff,    &adjS[cur ^ 1][s1 * 4]);

        // current chunk: adj + t -> P (A-frag layout: row m_, k = q_*8+kk)
        int4 aA = *(const int4*)&adjS[cur][sl0 * 4];
        int4 aB = *(const int4*)&adjS[cur][sl1 * 4];
        float4 tL = *(const float4*)&tS[jj * 32 + q_ * 8];
        float4 tH = *(const float4*)&tS[jj * 32 + q_ * 8 + 4];
        float tvk[8] = {tL.x, tL.y, tL.z, tL.w, tH.x, tH.y, tH.z, tH.w};
        int   avk[8] = {aA.x, aA.y, aA.z, aA.w, aB.x, aB.y, aB.z, aB.w};
        half8 af;
        #pragma unroll
        for (int k = 0; k < 8; ++k) {
            float e = s_i + tvk[k]; e = fmaxf(e, 0.2f * e);
            float p = avk[k] ? __expf(e - M_i) : 0.f;
            lsum += p;
            af[k] = (_Float16)p;
        }

        // MFMAs from staged LDS (sequential b128, conflict-free)
        #pragma unroll
        for (int n = 0; n < 8; ++n) {
            half8 bf = *(const half8*)&whS[cur][n * 512 + m_ * 32 + q_ * 8];
            acc[n] = __builtin_amdgcn_mfma_f32_16x16x32_f16(af, bf, acc[n], 0, 0, 0);
        }

        __syncthreads();   // drains this iter's async stage; guards buffers
    }

    // partial l: reduce over q-lanes (k-dim)
    lsum += __shfl_xor(lsum, 16, 64);
    lsum += __shfl_xor(lsum, 32, 64);
    if (q_ == 0) Pl[(size_t)jh * (B_ * N_) + girow] = lsum;

    // partial O: C/D layout row=q_*4+r, col=n*16+m_
    float* po = Po + (size_t)jh * ((size_t)B_ * N_ * F_)
              + (((size_t)((b << 11) + i0 + wv * 16)) << 7);
    #pragma unroll
    for (int n = 0; n < 8; ++n)
        #pragma unroll
        for (int r = 0; r < 4; ++r)
            po[(size_t)(q_ * 4 + r) * F_ + n * 16 + m_] = acc[n][r];
}

// ---------------------------------------------------------------------------
// Kernel 3: combine 4 j-slice partials: out = (sum Po) / (sum Pl), 0-guarded.
// ---------------------------------------------------------------------------
__global__ __launch_bounds__(256) void k_comb(
    const float* __restrict__ Po, const float* __restrict__ Pl,
    float* __restrict__ out)
{
    const int idx = blockIdx.x * 256 + threadIdx.x;   // 0..524287
    const int gi  = idx >> 5;
    const int o4  = (idx & 31) * 4;
    const size_t stride = (size_t)B_ * N_ * F_;

    float4 v = *(const float4*)&Po[(size_t)gi * F_ + o4];
    float  l = Pl[gi];
    #pragma unroll
    for (int jh = 1; jh < 4; ++jh) {
        float4 u = *(const float4*)&Po[jh * stride + (size_t)gi * F_ + o4];
        v.x += u.x; v.y += u.y; v.z += u.z; v.w += u.w;
        l += Pl[jh * (B_ * N_) + gi];
    }
    const float sc = l > 0.f ? 1.f / l : 0.f;
    float4 r = {v.x * sc, v.y * sc, v.z * sc, v.w * sc};
    *(float4*)&out[(size_t)gi * F_ + o4] = r;
}

extern "C" void kernel_launch(void* const* d_in, const int* in_sizes, int n_in,
                              void* d_out, int out_size, void* d_ws, size_t ws_size,
                              hipStream_t stream) {
    const float* h   = (const float*)d_in[0];
    const int*   adj = (const int*)d_in[1];
    const float* W   = (const float*)d_in[2];
    const float* a   = (const float*)d_in[3];
    float* out = (float*)d_out;

    char* ws = (char*)d_ws;
    _Float16* WhH = (_Float16*)ws;                        // 4 MB
    float* sv = (float*)(ws + (size_t)4 * 1024 * 1024);   // 64 KB
    float* tv = sv + (size_t)B_ * N_;                     // 64 KB
    float* Po = (float*)(ws + (size_t)8 * 1024 * 1024);   // 32 MB
    float* Pl = (float*)(ws + (size_t)40 * 1024 * 1024);  // 256 KB

    k_gemm<<<512, 256, 0, stream>>>(h, W, a, WhH, sv, tv);
    k_attn<<<1024, 256, 0, stream>>>(WhH, sv, tv, adj, Po, Pl);
    k_comb<<<2048, 256, 0, stream>>>(Po, Pl, out);
}